// Round 1
// baseline (86.780 us; speedup 1.0000x reference)
//
#include <hip/hip_runtime.h>
#include <math.h>

// Tropical (max-plus) matmul: y[b,o] = max_i (x[b,i] + W[o,i])
// x: [512,1024] f32, W: [1024,1024] f32 (both K-innermost), y: [512,1024] f32.
//
// Compute-bound on the vector ALU (no MFMA for max-plus, no fp32 MFMA on CDNA4).
// Split-K decomposition: 128 output tiles (64x64) x KS K-slices -> partial-max
// into workspace, then reduce. Exact (max is associative; adds identical to ref).

#define MDIM 512
#define NDIM 1024
#define KDIM 1024

#define BM 64
#define BN 64
#define BK 32
#define PAD 4          // row stride BM+4 = 68 floats: keeps 16B alignment for b128 frag reads
#define TM 4
#define TN 4
#define NTHREADS 256   // 16x16 thread grid, 4x4 outputs each

__global__ __launch_bounds__(NTHREADS)
void tropical_partial(const float* __restrict__ x, const float* __restrict__ W,
                      float* __restrict__ ws, int KC) {
    __shared__ float As[BK][BM + PAD];   // k-major so frag reads are contiguous in m
    __shared__ float Bs[BK][BN + PAD];

    const int tiles_n = NDIM / BN;                 // 16
    const int tile    = blockIdx.x;                // 0..127
    const int tm0     = (tile / tiles_n) * BM;
    const int tn0     = (tile % tiles_n) * BN;
    const int k0      = blockIdx.y * KC;           // this block's K-slice

    const int tid = threadIdx.x;
    // staging map: each thread loads 8 consecutive k for one row (2x float4)
    const int sm = tid >> 2;          // 0..63  (row within tile)
    const int sk = (tid & 3) * 8;     // 0,8,16,24 (k offset)
    // compute map
    const int tx = tid & 15;          // n-direction
    const int ty = tid >> 4;          // m-direction

    float acc[TM][TN];
#pragma unroll
    for (int i = 0; i < TM; ++i)
#pragma unroll
        for (int j = 0; j < TN; ++j) acc[i][j] = -INFINITY;

    for (int kt = 0; kt < KC; kt += BK) {
        const int kb = k0 + kt;
        // global loads issued before the barrier (in flight during wait)
        const float4 a0 = *(const float4*)&x[(size_t)(tm0 + sm) * KDIM + kb + sk];
        const float4 a1 = *(const float4*)&x[(size_t)(tm0 + sm) * KDIM + kb + sk + 4];
        const float4 b0 = *(const float4*)&W[(size_t)(tn0 + sm) * KDIM + kb + sk];
        const float4 b1 = *(const float4*)&W[(size_t)(tn0 + sm) * KDIM + kb + sk + 4];

        __syncthreads();   // previous iter's frag reads done before overwrite
        As[sk + 0][sm] = a0.x; As[sk + 1][sm] = a0.y;
        As[sk + 2][sm] = a0.z; As[sk + 3][sm] = a0.w;
        As[sk + 4][sm] = a1.x; As[sk + 5][sm] = a1.y;
        As[sk + 6][sm] = a1.z; As[sk + 7][sm] = a1.w;
        Bs[sk + 0][sm] = b0.x; Bs[sk + 1][sm] = b0.y;
        Bs[sk + 2][sm] = b0.z; Bs[sk + 3][sm] = b0.w;
        Bs[sk + 4][sm] = b1.x; Bs[sk + 5][sm] = b1.y;
        Bs[sk + 6][sm] = b1.z; Bs[sk + 7][sm] = b1.w;
        __syncthreads();

#pragma unroll 8
        for (int kk = 0; kk < BK; ++kk) {
            const float4 av = *(const float4*)&As[kk][ty * TM];
            const float4 bv = *(const float4*)&Bs[kk][tx * TN];
            const float a[4] = {av.x, av.y, av.z, av.w};
            const float b[4] = {bv.x, bv.y, bv.z, bv.w};
#pragma unroll
            for (int i = 0; i < TM; ++i)
#pragma unroll
                for (int j = 0; j < TN; ++j)
                    acc[i][j] = fmaxf(acc[i][j], a[i] + b[j]);
        }
    }

    // write this K-slice's partial tile
    float* wsl = ws + (size_t)blockIdx.y * MDIM * NDIM;
#pragma unroll
    for (int i = 0; i < TM; ++i) {
        const float4 v = make_float4(acc[i][0], acc[i][1], acc[i][2], acc[i][3]);
        *(float4*)&wsl[(size_t)(tm0 + ty * TM + i) * NDIM + tn0 + tx * TN] = v;
    }
}

__global__ __launch_bounds__(NTHREADS)
void tropical_reduce(const float* __restrict__ ws, float* __restrict__ out, int KS) {
    const int i = blockIdx.x * NTHREADS + threadIdx.x;       // float4 index
    const int stride = MDIM * NDIM / 4;
    if (i >= stride) return;
    const float4* w4 = (const float4*)ws;
    float4 m = w4[i];
    for (int s = 1; s < KS; ++s) {
        const float4 v = w4[(size_t)s * stride + i];
        m.x = fmaxf(m.x, v.x); m.y = fmaxf(m.y, v.y);
        m.z = fmaxf(m.z, v.z); m.w = fmaxf(m.w, v.w);
    }
    ((float4*)out)[i] = m;
}

extern "C" void kernel_launch(void* const* d_in, const int* in_sizes, int n_in,
                              void* d_out, int out_size, void* d_ws, size_t ws_size,
                              hipStream_t stream) {
    const float* x = (const float*)d_in[0];
    const float* W = (const float*)d_in[1];
    float* out = (float*)d_out;
    float* ws  = (float*)d_ws;

    const size_t slice = (size_t)MDIM * NDIM * sizeof(float);  // 2 MB per K-slice
    int KS = 8;
    while (KS > 1 && (size_t)KS * slice > ws_size) KS >>= 1;

    const int ntiles = (MDIM / BM) * (NDIM / BN);  // 128

    if ((size_t)KS * slice > ws_size) {
        // tiny-workspace fallback: single slice straight into out, no reduce
        tropical_partial<<<dim3(ntiles, 1), NTHREADS, 0, stream>>>(x, W, out, KDIM);
        return;
    }

    const int KC = KDIM / KS;
    tropical_partial<<<dim3(ntiles, KS), NTHREADS, 0, stream>>>(x, W, ws, KC);

    const int nvec4 = MDIM * NDIM / 4;
    tropical_reduce<<<(nvec4 + NTHREADS - 1) / NTHREADS, NTHREADS, 0, stream>>>(ws, out, KS);
}